// Round 9
// baseline (428.202 us; speedup 1.0000x reference)
//
#include <hip/hip_runtime.h>
#include <math.h>

#define NSPEC 7
#define NMOL 1024
#define APM 48
#define NATOMS (NMOL * APM)   // 49152
#define FDIM 384

typedef unsigned short u16;
typedef unsigned int u32;
typedef __attribute__((ext_vector_type(8))) short short8;
typedef __attribute__((ext_vector_type(4))) float floatx4;

#define BUCKET_BLOCKS (NATOMS / 256)   // 192

// ws layout (bytes): g_cnt[8] @0, bucket u16[7*NATOMS] @32. ~0.69 MB.
#define WS_BKT_OFF 32

#define BUFST 264   // LDS activation row stride in u16 (16B-aligned)

__device__ __forceinline__ float celu01(float x) {
    float e = fmaf(0.1f, __expf(x * 10.0f), -0.1f);   // validated R4-R7
    return x > 0.0f ? x : e;
}

__device__ __forceinline__ u16 bfr(float f) {  // fp32 -> bf16 RNE
    u32 u = __float_as_uint(f);
    u += 0x7fffu + ((u >> 16) & 1u);
    return (u16)(u >> 16);
}

__device__ __forceinline__ float bf2f(short s) {
    return __uint_as_float(((u32)(u16)s) << 16);
}

union U8 { short8 v; u16 u[8]; };

// Load one B fragment (8 fp32 -> bf16x8) straight from row-major fp32 W.
// Bit-identical to the old pack path (same bfr), so numerics are unchanged.
__device__ __forceinline__ short8 ld_frag(const float* __restrict__ p) {
    float4 a = ((const float4*)p)[0];
    float4 b = ((const float4*)p)[1];
    U8 x;
    x.u[0] = bfr(a.x); x.u[1] = bfr(a.y); x.u[2] = bfr(a.z); x.u[3] = bfr(a.w);
    x.u[4] = bfr(b.x); x.u[5] = bfr(b.y); x.u[6] = bfr(b.z); x.u[7] = bfr(b.w);
    return x.v;
}

// ---------------- prep: bucket + d_out zero only (R1-class, ~3 us) ----------------
__global__ void prep_kernel(const int* __restrict__ species,
                            int* __restrict__ g_cnt, u16* __restrict__ bucket,
                            float* __restrict__ out) {
    int t = threadIdx.x;
    int bx = blockIdx.x;
    if (bx == 0) {   // zero out[1024]; mlp runs strictly after us on the stream
        float4 z = {0.f, 0.f, 0.f, 0.f};
        ((float4*)out)[t] = z;
    }
    __shared__ int l_cnt[NSPEC];
    __shared__ int l_base[NSPEC];
    if (t < NSPEC) l_cnt[t] = 0;
    __syncthreads();
    int i = bx * 256 + t;
    int s = species[i];
    int lpos = atomicAdd(&l_cnt[s], 1);
    __syncthreads();
    if (t < NSPEC) l_base[t] = atomicAdd(&g_cnt[t], l_cnt[t]);
    __syncthreads();
    bucket[s * NATOMS + l_base[s] + lpos] = (u16)i;
}

// ---------------- MFMA layer: 32 atoms/wave, fp32-W direct, ping-pong B ----------------
// wsp = W + s*N*K (species base, row-major [N][K]). Lane reads rows t*16+nl,
// k = kg*32 + kg4*8 .. +8 : two float4 per kg with immediate offsets.
// NT is even for all layers -> explicit bA/bB ping-pong, no dynamic indexing.
template <int KGS, int NT>
__device__ __forceinline__ void run_layer(const short8* af0, const short8* af1,
                                          const float* __restrict__ wsp,
                                          const float* __restrict__ bias,
                                          u16* __restrict__ outbuf, int lane) {
    const int nl = lane & 15, kg4 = lane >> 4;
    const int K = KGS * 32;
    short8 bA[KGS], bB[KGS];
    {
        const float* wr = wsp + (size_t)nl * K + kg4 * 8;   // tile 0
#pragma unroll
        for (int kg = 0; kg < KGS; ++kg) bA[kg] = ld_frag(wr + kg * 32);
    }
#pragma unroll
    for (int tt = 0; tt < NT / 2; ++tt) {
        int t0 = 2 * tt;
        // ---- even tile t0 (bA), prefetch t0+1 into bB ----
        {
            const float* wr = wsp + (size_t)((t0 + 1) * 16 + nl) * K + kg4 * 8;
#pragma unroll
            for (int kg = 0; kg < KGS; ++kg) bB[kg] = ld_frag(wr + kg * 32);
        }
        {
            floatx4 acc0 = {0.f, 0.f, 0.f, 0.f};
            floatx4 acc1 = {0.f, 0.f, 0.f, 0.f};
#pragma unroll
            for (int kg = 0; kg < KGS; ++kg) {
                acc0 = __builtin_amdgcn_mfma_f32_16x16x32_bf16(af0[kg], bA[kg], acc0, 0, 0, 0);
                acc1 = __builtin_amdgcn_mfma_f32_16x16x32_bf16(af1[kg], bA[kg], acc1, 0, 0, 0);
            }
            float bn = bias[t0 * 16 + nl];
#pragma unroll
            for (int r = 0; r < 4; ++r) {
                outbuf[(kg4 * 4 + r) * BUFST + t0 * 16 + nl] = bfr(celu01(acc0[r] + bn));
                outbuf[(16 + kg4 * 4 + r) * BUFST + t0 * 16 + nl] = bfr(celu01(acc1[r] + bn));
            }
        }
        // ---- odd tile t0+1 (bB), prefetch t0+2 into bA ----
        if (t0 + 2 < NT) {
            const float* wr = wsp + (size_t)((t0 + 2) * 16 + nl) * K + kg4 * 8;
#pragma unroll
            for (int kg = 0; kg < KGS; ++kg) bA[kg] = ld_frag(wr + kg * 32);
        }
        {
            floatx4 acc0 = {0.f, 0.f, 0.f, 0.f};
            floatx4 acc1 = {0.f, 0.f, 0.f, 0.f};
#pragma unroll
            for (int kg = 0; kg < KGS; ++kg) {
                acc0 = __builtin_amdgcn_mfma_f32_16x16x32_bf16(af0[kg], bB[kg], acc0, 0, 0, 0);
                acc1 = __builtin_amdgcn_mfma_f32_16x16x32_bf16(af1[kg], bB[kg], acc1, 0, 0, 0);
            }
            float bn = bias[(t0 + 1) * 16 + nl];
#pragma unroll
            for (int r = 0; r < 4; ++r) {
                outbuf[(kg4 * 4 + r) * BUFST + (t0 + 1) * 16 + nl] = bfr(celu01(acc0[r] + bn));
                outbuf[(16 + kg4 * 4 + r) * BUFST + (t0 + 1) * 16 + nl] = bfr(celu01(acc1[r] + bn));
            }
        }
    }
}

template <int KGS>
__device__ __forceinline__ void load_a_lds(const u16* __restrict__ buf,
                                           short8* af0, short8* af1, int lane) {
    int nl = lane & 15, kg4 = lane >> 4;
#pragma unroll
    for (int kg = 0; kg < KGS; ++kg) {
        af0[kg] = *reinterpret_cast<const short8*>(buf + (size_t)nl * BUFST + kg * 32 + kg4 * 8);
        af1[kg] = *reinterpret_cast<const short8*>(buf + (size_t)(16 + nl) * BUFST + kg * 32 + kg4 * 8);
    }
}

// R5-proven skeleton: 128 thr (2 waves), wave-private LDS, barrier-free,
// (128,2) -> 256-VGPR cap, XCD species pinning via bx&7.
__global__ __launch_bounds__(128, 2) void mlp_kernel(
    const float* __restrict__ aev,
    const float* __restrict__ W1, const float* __restrict__ W2, const float* __restrict__ W3,
    const float* __restrict__ b1, const float* __restrict__ b2, const float* __restrict__ b3,
    const float* __restrict__ W4, const float* __restrict__ b4,
    const int* __restrict__ g_cnt, const u16* __restrict__ bucket,
    float* __restrict__ out) {
    int bx = blockIdx.x;
    int s = bx & 7;
    if (s >= NSPEC) return;
    int chunk = bx >> 3;
    int cnt = g_cnt[s];
    int w = threadIdx.x >> 6, lane = threadIdx.x & 63;
    int base = chunk * 64 + w * 32;      // this wave's 32 atoms
    if (base >= cnt) return;

    __shared__ __align__(16) u16 bufs[2][32 * BUFST];  // 33792 B/block
    u16* buf = &bufs[w][0];

    int nl = lane & 15, kg4 = lane >> 4;

    // ---- layer 1 A: gather 32 fp32 aev rows -> bf16 frags ----
    short8 af0[12], af1[12];
    {
        int i0 = base + nl;       if (i0 >= cnt) i0 = cnt - 1;
        int i1 = base + 16 + nl;  if (i1 >= cnt) i1 = cnt - 1;
        int a0 = (int)bucket[s * NATOMS + i0];
        int a1 = (int)bucket[s * NATOMS + i1];
        const float* ar0 = aev + (size_t)a0 * FDIM;
        const float* ar1 = aev + (size_t)a1 * FDIM;
#pragma unroll
        for (int kg = 0; kg < 12; ++kg) {
            af0[kg] = ld_frag(ar0 + kg * 32 + kg4 * 8);
            af1[kg] = ld_frag(ar1 + kg * 32 + kg4 * 8);
        }
    }

    // ---- layer 1: 384 -> 256 ----
    run_layer<12, 16>(af0, af1, W1 + (size_t)s * 256 * 384, b1 + s * 256, buf, lane);

    // ---- layer 2: 256 -> 192 ----
    short8 c0[8], c1[8];
    load_a_lds<8>(buf, c0, c1, lane);
    run_layer<8, 12>(c0, c1, W2 + (size_t)s * 192 * 256, b2 + s * 192, buf, lane);

    // ---- layer 3: 192 -> 160 ----
    short8 d0[6], d1[6];
    load_a_lds<6>(buf, d0, d1, lane);
    run_layer<6, 10>(d0, d1, W3 + (size_t)s * 160 * 192, b3 + s * 160, buf, lane);

    // ---- layer 4: 160 -> 1 (fp32 VALU), 2 lanes/atom, + molecule scatter-add ----
    {
        int m = lane >> 1, q = lane & 1;
        const u16* h = buf + (size_t)m * BUFST + q * 80;
        const float* w4s = W4 + s * 160 + q * 80;
        float p = 0.f;
#pragma unroll
        for (int c = 0; c < 10; ++c) {
            short8 hv = *reinterpret_cast<const short8*>(h + c * 8);
            const float4* wp4 = (const float4*)(w4s + c * 8);
            float4 wa = wp4[0], wb = wp4[1];
            p += bf2f(hv[0]) * wa.x + bf2f(hv[1]) * wa.y + bf2f(hv[2]) * wa.z + bf2f(hv[3]) * wa.w;
            p += bf2f(hv[4]) * wb.x + bf2f(hv[5]) * wb.y + bf2f(hv[6]) * wb.z + bf2f(hv[7]) * wb.w;
        }
        p += __shfl_down(p, 1, 2);
        int idx = base + m;
        if (q == 0 && idx < cnt) {
            int atom = (int)bucket[s * NATOMS + idx];
            atomicAdd(&out[atom / APM], p + b4[s]);
        }
    }
}

extern "C" void kernel_launch(void* const* d_in, const int* in_sizes, int n_in,
                              void* d_out, int out_size, void* d_ws, size_t ws_size,
                              hipStream_t stream) {
    const int* species = (const int*)d_in[0];
    const float* aev = (const float*)d_in[1];
    const float* W1 = (const float*)d_in[2];
    const float* b1 = (const float*)d_in[3];
    const float* W2 = (const float*)d_in[4];
    const float* b2 = (const float*)d_in[5];
    const float* W3 = (const float*)d_in[6];
    const float* b3 = (const float*)d_in[7];
    const float* W4 = (const float*)d_in[8];
    const float* b4 = (const float*)d_in[9];
    float* out = (float*)d_out;

    unsigned char* wsb = (unsigned char*)d_ws;
    int* g_cnt = (int*)wsb;
    u16* bucket = (u16*)(wsb + WS_BKT_OFF);

    hipMemsetAsync(g_cnt, 0, 8 * sizeof(int), stream);

    prep_kernel<<<BUCKET_BLOCKS, 256, 0, stream>>>(species, g_cnt, bucket, out);

    mlp_kernel<<<8 * (NATOMS / 64), 128, 0, stream>>>(
        aev, W1, W2, W3, b1, b2, b3, W4, b4, g_cnt, bucket, out);
}

// Round 10
// 281.688 us; speedup vs baseline: 1.5201x; 1.5201x over previous
//
#include <hip/hip_runtime.h>
#include <hip/hip_bf16.h>
#include <math.h>

#define NSPEC 7
#define NMOL 1024
#define APM 48
#define NATOMS (NMOL * APM)   // 49152
#define FDIM 384

typedef unsigned short u16;
typedef unsigned int u32;
typedef __attribute__((ext_vector_type(8))) short short8;
typedef __attribute__((ext_vector_type(4))) float floatx4;

#define BUCKET_BLOCKS (NATOMS / 256)   // 192

// ws layout (bytes): g_cnt[8] @0, bucket u16[7*NATOMS] @32. ~0.69 MB.
#define WS_BKT_OFF 32

#define BUFST 264   // LDS activation row stride in u16 (16B-aligned)

__device__ __forceinline__ float celu01(float x) {
    float e = fmaf(0.1f, __expf(x * 10.0f), -0.1f);   // validated R4-R9
    return x > 0.0f ? x : e;
}

__device__ __forceinline__ u16 bfr(float f) {  // fp32 -> bf16 RNE (layer-4 path)
    u32 u = __float_as_uint(f);
    u += 0x7fffu + ((u >> 16) & 1u);
    return (u16)(u >> 16);
}

__device__ __forceinline__ float bf2f(short s) {
    return __uint_as_float(((u32)(u16)s) << 16);
}

union CV8 { __hip_bfloat162 h[4]; short8 v; };

// 2x float4 -> short8 bf16, RNE (same rounding as bfr -> identical numerics).
__device__ __forceinline__ short8 cvt_frag(float4 a, float4 b) {
    CV8 x;
    x.h[0] = __float22bfloat162_rn({a.x, a.y});
    x.h[1] = __float22bfloat162_rn({a.z, a.w});
    x.h[2] = __float22bfloat162_rn({b.x, b.y});
    x.h[3] = __float22bfloat162_rn({b.z, b.w});
    return x.v;
}

// ---------------- prep: bucket + d_out zero only (R9-proven, ~3 us) ----------------
__global__ void prep_kernel(const int* __restrict__ species,
                            int* __restrict__ g_cnt, u16* __restrict__ bucket,
                            float* __restrict__ out) {
    int t = threadIdx.x;
    int bx = blockIdx.x;
    if (bx == 0) {   // zero out[1024]; mlp runs strictly after us on the stream
        float4 z = {0.f, 0.f, 0.f, 0.f};
        ((float4*)out)[t] = z;
    }
    __shared__ int l_cnt[NSPEC];
    __shared__ int l_base[NSPEC];
    if (t < NSPEC) l_cnt[t] = 0;
    __syncthreads();
    int i = bx * 256 + t;
    int s = species[i];
    int lpos = atomicAdd(&l_cnt[s], 1);
    __syncthreads();
    if (t < NSPEC) l_base[t] = atomicAdd(&g_cnt[t], l_cnt[t]);
    __syncthreads();
    bucket[s * NATOMS + l_base[s] + lpos] = (u16)i;
}

// ---------------- MFMA layer: fp32 W direct, chunk-pipelined, spill-safe ----------------
// W row-major [N][K], species pre-offset. Lane (nl,kg4) reads row t*16+nl,
// cols kg*32+kg4*8. B consumed in NC chunks of CH frags; 2 fp32 slots rotate.
// Peak live regs ~ af(2*KGS*4) + 2*CH*8 fp32 + CH*4 bf16 + 8 acc + addr < 256.
// #pragma unroll 1 on the tile loop stops cross-tile load batching (R9 spill).
template <int KGS, int NT, int CH>
__device__ __forceinline__ void run_layer(const short8* af0, const short8* af1,
                                          const float* __restrict__ wsp,
                                          const float* __restrict__ bias,
                                          u16* __restrict__ outbuf, int lane) {
    const int nl = lane & 15, kg4 = lane >> 4;
    const int K = KGS * 32;
    constexpr int NC = KGS / CH;
    static_assert(NC * CH == KGS, "chunking must tile KGS");

#pragma unroll 1
    for (int t = 0; t < NT; ++t) {
        const float* wr = wsp + (size_t)(t * 16 + nl) * K + kg4 * 8;
        float4 F[2][CH][2];
        // preload chunk 0 (and 1 if present)
#pragma unroll
        for (int j = 0; j < CH; ++j) {
            F[0][j][0] = ((const float4*)(wr + (0 * CH + j) * 32))[0];
            F[0][j][1] = ((const float4*)(wr + (0 * CH + j) * 32))[1];
        }
        if (NC > 1) {
#pragma unroll
            for (int j = 0; j < CH; ++j) {
                F[1][j][0] = ((const float4*)(wr + (1 * CH + j) * 32))[0];
                F[1][j][1] = ((const float4*)(wr + (1 * CH + j) * 32))[1];
            }
        }
        floatx4 acc0 = {0.f, 0.f, 0.f, 0.f};
        floatx4 acc1 = {0.f, 0.f, 0.f, 0.f};
#pragma unroll
        for (int c = 0; c < NC; ++c) {
            short8 B[CH];
#pragma unroll
            for (int j = 0; j < CH; ++j)
                B[j] = cvt_frag(F[c & 1][j][0], F[c & 1][j][1]);
            if (c + 2 < NC) {
#pragma unroll
                for (int j = 0; j < CH; ++j) {
                    F[c & 1][j][0] = ((const float4*)(wr + ((c + 2) * CH + j) * 32))[0];
                    F[c & 1][j][1] = ((const float4*)(wr + ((c + 2) * CH + j) * 32))[1];
                }
            }
#pragma unroll
            for (int j = 0; j < CH; ++j) {
                int kg = c * CH + j;
                acc0 = __builtin_amdgcn_mfma_f32_16x16x32_bf16(af0[kg], B[j], acc0, 0, 0, 0);
                acc1 = __builtin_amdgcn_mfma_f32_16x16x32_bf16(af1[kg], B[j], acc1, 0, 0, 0);
            }
        }
        float bn = bias[t * 16 + nl];
#pragma unroll
        for (int r = 0; r < 4; ++r) {
            outbuf[(kg4 * 4 + r) * BUFST + t * 16 + nl] = bfr(celu01(acc0[r] + bn));
            outbuf[(16 + kg4 * 4 + r) * BUFST + t * 16 + nl] = bfr(celu01(acc1[r] + bn));
        }
    }
}

template <int KGS>
__device__ __forceinline__ void load_a_lds(const u16* __restrict__ buf,
                                           short8* af0, short8* af1, int lane) {
    int nl = lane & 15, kg4 = lane >> 4;
#pragma unroll
    for (int kg = 0; kg < KGS; ++kg) {
        af0[kg] = *reinterpret_cast<const short8*>(buf + (size_t)nl * BUFST + kg * 32 + kg4 * 8);
        af1[kg] = *reinterpret_cast<const short8*>(buf + (size_t)(16 + nl) * BUFST + kg * 32 + kg4 * 8);
    }
}

// R5-proven skeleton: 128 thr (2 waves), wave-private LDS, barrier-free,
// (128,2) -> 256-VGPR cap, XCD species pinning via bx&7.
__global__ __launch_bounds__(128, 2) void mlp_kernel(
    const float* __restrict__ aev,
    const float* __restrict__ W1, const float* __restrict__ W2, const float* __restrict__ W3,
    const float* __restrict__ b1, const float* __restrict__ b2, const float* __restrict__ b3,
    const float* __restrict__ W4, const float* __restrict__ b4,
    const int* __restrict__ g_cnt, const u16* __restrict__ bucket,
    float* __restrict__ out) {
    int bx = blockIdx.x;
    int s = bx & 7;
    if (s >= NSPEC) return;
    int chunk = bx >> 3;
    int cnt = g_cnt[s];
    int w = threadIdx.x >> 6, lane = threadIdx.x & 63;
    int base = chunk * 64 + w * 32;      // this wave's 32 atoms
    if (base >= cnt) return;

    __shared__ __align__(16) u16 bufs[2][32 * BUFST];  // 33792 B/block
    u16* buf = &bufs[w][0];

    int nl = lane & 15, kg4 = lane >> 4;

    // ---- layer 1 A: gather 32 fp32 aev rows -> bf16 frags ----
    short8 af0[12], af1[12];
    {
        int i0 = base + nl;       if (i0 >= cnt) i0 = cnt - 1;
        int i1 = base + 16 + nl;  if (i1 >= cnt) i1 = cnt - 1;
        int a0 = (int)bucket[s * NATOMS + i0];
        int a1 = (int)bucket[s * NATOMS + i1];
        const float* ar0 = aev + (size_t)a0 * FDIM;
        const float* ar1 = aev + (size_t)a1 * FDIM;
#pragma unroll
        for (int kg = 0; kg < 12; ++kg) {
            const float4* p0 = (const float4*)(ar0 + kg * 32 + kg4 * 8);
            const float4* p1 = (const float4*)(ar1 + kg * 32 + kg4 * 8);
            af0[kg] = cvt_frag(p0[0], p0[1]);
            af1[kg] = cvt_frag(p1[0], p1[1]);
        }
    }

    // ---- layer 1: 384 -> 256 (KGS=12, CH=3 -> NC=4) ----
    run_layer<12, 16, 3>(af0, af1, W1 + (size_t)s * 256 * 384, b1 + s * 256, buf, lane);

    // ---- layer 2: 256 -> 192 (KGS=8, CH=4 -> NC=2) ----
    short8 c0[8], c1[8];
    load_a_lds<8>(buf, c0, c1, lane);
    run_layer<8, 12, 4>(c0, c1, W2 + (size_t)s * 192 * 256, b2 + s * 192, buf, lane);

    // ---- layer 3: 192 -> 160 (KGS=6, CH=3 -> NC=2) ----
    short8 d0[6], d1[6];
    load_a_lds<6>(buf, d0, d1, lane);
    run_layer<6, 10, 3>(d0, d1, W3 + (size_t)s * 160 * 192, b3 + s * 160, buf, lane);

    // ---- layer 4: 160 -> 1 (fp32 VALU), 2 lanes/atom, + molecule scatter-add ----
    {
        int m = lane >> 1, q = lane & 1;
        const u16* h = buf + (size_t)m * BUFST + q * 80;
        const float* w4s = W4 + s * 160 + q * 80;
        float p = 0.f;
#pragma unroll
        for (int c = 0; c < 10; ++c) {
            short8 hv = *reinterpret_cast<const short8*>(h + c * 8);
            const float4* wp4 = (const float4*)(w4s + c * 8);
            float4 wa = wp4[0], wb = wp4[1];
            p += bf2f(hv[0]) * wa.x + bf2f(hv[1]) * wa.y + bf2f(hv[2]) * wa.z + bf2f(hv[3]) * wa.w;
            p += bf2f(hv[4]) * wb.x + bf2f(hv[5]) * wb.y + bf2f(hv[6]) * wb.z + bf2f(hv[7]) * wb.w;
        }
        p += __shfl_down(p, 1, 2);
        int idx = base + m;
        if (q == 0 && idx < cnt) {
            int atom = (int)bucket[s * NATOMS + idx];
            atomicAdd(&out[atom / APM], p + b4[s]);
        }
    }
}

extern "C" void kernel_launch(void* const* d_in, const int* in_sizes, int n_in,
                              void* d_out, int out_size, void* d_ws, size_t ws_size,
                              hipStream_t stream) {
    const int* species = (const int*)d_in[0];
    const float* aev = (const float*)d_in[1];
    const float* W1 = (const float*)d_in[2];
    const float* b1 = (const float*)d_in[3];
    const float* W2 = (const float*)d_in[4];
    const float* b2 = (const float*)d_in[5];
    const float* W3 = (const float*)d_in[6];
    const float* b3 = (const float*)d_in[7];
    const float* W4 = (const float*)d_in[8];
    const float* b4 = (const float*)d_in[9];
    float* out = (float*)d_out;

    unsigned char* wsb = (unsigned char*)d_ws;
    int* g_cnt = (int*)wsb;
    u16* bucket = (u16*)(wsb + WS_BKT_OFF);

    hipMemsetAsync(g_cnt, 0, 8 * sizeof(int), stream);

    prep_kernel<<<BUCKET_BLOCKS, 256, 0, stream>>>(species, g_cnt, bucket, out);

    mlp_kernel<<<8 * (NATOMS / 64), 128, 0, stream>>>(
        aev, W1, W2, W3, b1, b2, b3, W4, b4, g_cnt, bucket, out);
}